// Round 12
// baseline (370.900 us; speedup 1.0000x reference)
//
#include <hip/hip_runtime.h>
#include <math.h>

#define BB 2
#define NN 512
#define DD 128
#define HH 8
#define DKK 16
#define TR 64            // tile rows
#define NT (NN / TR)     // 8 tiles per (b,n)
#define ETS 516          // padded ET row stride (516 % 32 = 4 -> conflict-free RMW)

typedef __attribute__((ext_vector_type(8))) short short8;
typedef __attribute__((ext_vector_type(4))) float f32x4;

__device__ __forceinline__ float dot4(float4 a, float4 b) {
    return a.x*b.x + a.y*b.y + a.z*b.z + a.w*b.w;
}
// RNE f32 -> bf16 pack (a in low, b in high)
__device__ __forceinline__ unsigned pk_bf16(float a, float b) {
    unsigned ua = __float_as_uint(a), ub = __float_as_uint(b);
    ua = (ua + 0x7FFFu + ((ua >> 16) & 1u)) >> 16;
    ub = (ub + 0x7FFFu + ((ub >> 16) & 1u)) >> 16;
    return ua | (ub << 16);
}

// ---------------- Kernel 1: QKV projection + W_egT staging ----------------
__global__ __launch_bounds__(128)
void qkv_kernel(const float* __restrict__ n_in,
                const float* __restrict__ W_qkv,
                const float* __restrict__ W_g,
                const float* __restrict__ W_e,
                float* __restrict__ Qw, float* __restrict__ Kw,
                float* __restrict__ Vw, float* __restrict__ WegT)
{
    const int bid = blockIdx.x;
    if (bid >= BB * NN) {                    // 16 trailing blocks: WegT[col][d]
        const int col = bid - BB * NN;       // 0..15
        const int t = threadIdx.x;           // 0..127
        WegT[col * DD + t] = (col < 8) ? W_e[t * HH + col]
                                       : W_g[t * HH + (col - 8)];
        return;
    }
    __shared__ float nrow[DD];
    const int bn = bid;
    const int b  = bn >> 9;
    const int nr = bn & 511;
    const int t  = threadIdx.x;
    nrow[t] = n_in[(size_t)bn * DD + t];
    __syncthreads();
    const int h = t >> 4, dk = t & 15;
    const size_t dst = ((size_t)(b * HH + h) * NN + nr) * DKK + dk;
    float accq = 0.f, acck = 0.f, accv = 0.f;
    #pragma unroll 8
    for (int d = 0; d < DD; ++d) {
        const float nv = nrow[d];
        const float* wr = W_qkv + (size_t)d * 3 * DD;
        accq += nv * wr[t];
        acck += nv * wr[t + 128];
        accv += nv * wr[t + 256];
    }
    Qw[dst] = accq;
    Kw[dst] = acck;
    Vw[dst] = accv;
}

// ---------------- Kernel 2: fully fused QK + E/G (MFMA) + e_out + softmax/AV + n_out
// One block per (b,n), 512 threads = 8 waves. TR=64 tiles; MFMA wave-group
// alternates by tile parity. LDS ~33.7KB + VGPR<=64 -> 4 blocks/CU, grid
// 1024 = one full round across 256 CUs.
__global__ __launch_bounds__(512, 8)
void eg_kernel(const float* __restrict__ e,
               const float* __restrict__ WegT,
               const float* __restrict__ O_e,
               const float* __restrict__ Qw,
               const float* __restrict__ Kw,
               const float* __restrict__ Vw,
               const float* __restrict__ O_n,
               float* __restrict__ n_out,
               float* __restrict__ e_out)
{
    __shared__ __align__(16) uint4 ebuf4[TR * 16];   // 16KB bf16 tile (single)
    __shared__ __align__(16) float ET[HH * ETS];     // 16.5KB persistent _E [h][m]
    __shared__ float Gred[64];
    __shared__ float dc[HH];
    __shared__ __align__(16) float vout[DD];

    const int t    = threadIdx.x;
    const int bn   = blockIdx.x;
    const int b    = bn >> 9;
    const int nr   = bn & 511;
    const int wq   = t >> 6;
    const int lane = t & 63;
    const int c    = lane & 15;      // MFMA C/D col (= W col / head)
    const int mq   = lane >> 4;      // C/D row group; also A/B k-group
    const int wgrp = wq & 3;         // m-block within tile
    const int wpar = wq >> 2;        // group parity (0: even tiles, 1: odd)
    const int c4o  = t & 31;         // e_out float4 column
    const int mr0  = t >> 5;         // e_out row base 0..15

    const float4* __restrict__ e4    = (const float4*)e + (size_t)bn * NN * 32;
    const float4* __restrict__ WegT4 = (const float4*)WegT;

    // ---- B fragments: W[col=c][k] -> bf16, 4 k-steps (16 VGPR) ----
    short8 wB[4];
    #pragma unroll
    for (int kb = 0; kb < 4; ++kb) {
        const float4 wa = WegT4[c * 32 + kb * 8 + mq * 2];
        const float4 wb = WegT4[c * 32 + kb * 8 + mq * 2 + 1];
        uint4 u;
        u.x = pk_bf16(wa.x, wa.y); u.y = pk_bf16(wa.z, wa.w);
        u.z = pk_bf16(wb.x, wb.y); u.w = pk_bf16(wb.z, wb.w);
        wB[kb] = *(short8*)&u;
    }

    // stage-load regs: 4 float4 (16 VGPR)
    float4 pa0, pb0, pa1, pb1;

    #define STAGE_LOAD(tile)                                                  \
    {                                                                         \
        const float4* __restrict__ sp = e4 + (size_t)(tile) * 2048 + 2 * t;   \
        pa0 = sp[0];    pb0 = sp[1];                                          \
        pa1 = sp[1024]; pb1 = sp[1025];                                       \
    }
    // uint4 u covers f32-float4 pair (2u, 2u+1); row = u>>4, col ck = u&15
    #define STAGE_WRITE(U, A, B)                                              \
    {                                                                         \
        const int u_ = (U), ms = u_ >> 4, ck = u_ & 15;                       \
        uint4 x;                                                              \
        x.x = pk_bf16(A.x, A.y); x.y = pk_bf16(A.z, A.w);                     \
        x.z = pk_bf16(B.x, B.y); x.w = pk_bf16(B.z, B.w);                     \
        ebuf4[ms * 16 + (ck ^ (ms & 15))] = x;                                \
    }
    #define STAGE_WRITE_ALL()                                                 \
    {                                                                         \
        STAGE_WRITE(t, pa0, pb0); STAGE_WRITE(t + 512, pa1, pb1);             \
    }

    float ga0 = 0.f, ga1 = 0.f, ga2 = 0.f, ga3 = 0.f;

    // ---- prologue: issue tile-0 e loads (HBM), then QK scores (L2) ----
    STAGE_LOAD(0);

    {   // wave wq = head h; clamped scores -> ET[h][m]
        const int h = wq;
        const float4* __restrict__ qp =
            (const float4*)(Qw + ((size_t)(b * HH + h) * NN + nr) * DKK);
        const float4 q0 = qp[0], q1 = qp[1], q2 = qp[2], q3 = qp[3];
        const float4* __restrict__ kb =
            (const float4*)(Kw + ((size_t)(b * HH + h) * NN) * DKK);
        #pragma unroll
        for (int k = 0; k < 8; ++k) {
            const int m = k * 64 + lane;
            float s = dot4(q0, kb[m * 4 + 0]) + dot4(q1, kb[m * 4 + 1])
                    + dot4(q2, kb[m * 4 + 2]) + dot4(q3, kb[m * 4 + 3]);
            s *= 0.25f;
            ET[h * ETS + m] = fminf(5.f, fmaxf(-5.f, s));
        }
    }

    STAGE_WRITE_ALL();
    asm volatile("s_waitcnt lgkmcnt(0)" ::: "memory");
    __builtin_amdgcn_s_barrier();

    #pragma unroll
    for (int tt = 0; tt < NT; ++tt) {
        // prefetch next tile into regs (stays in flight across the MFMA)
        if (tt + 1 < NT) STAGE_LOAD(tt + 1);

        // ---- MFMA: tile parity selects the active 4-wave group ----
        if (wpar == (tt & 1)) {
            const int mrow = wgrp * 16 + c;
            f32x4 acc = {0.f, 0.f, 0.f, 0.f};
            #pragma unroll
            for (int kb = 0; kb < 4; ++kb) {
                const int ck = kb * 4 + mq;
                uint4 av = ebuf4[mrow * 16 + (ck ^ (mrow & 15))];
                acc = __builtin_amdgcn_mfma_f32_16x16x32_bf16(
                          *(short8*)&av, wB[kb], acc, 0, 0, 0);
            }
            // ---- epilogue: _E = acc + clamped_score (LDS RMW) / G accumulate ----
            const int mloc = tt * TR + wgrp * 16 + mq * 4;
            if (c < 8) {
                float4 prev = *(float4*)&ET[c * ETS + mloc];
                prev.x += acc[0]; prev.y += acc[1];
                prev.z += acc[2]; prev.w += acc[3];
                *(float4*)&ET[c * ETS + mloc] = prev;
            } else {
                ga0 += 1.f / (1.f + __expf(-acc[0]));
                ga1 += 1.f / (1.f + __expf(-acc[1]));
                ga2 += 1.f / (1.f + __expf(-acc[2]));
                ga3 += 1.f / (1.f + __expf(-acc[3]));
            }
        }
        asm volatile("s_waitcnt lgkmcnt(0)" ::: "memory");
        __builtin_amdgcn_s_barrier();   // ebuf reads done; ET writes visible

        // ---- refill ebuf from prefetched regs ----
        if (tt + 1 < NT) {
            STAGE_WRITE_ALL();          // compiler waits the prefetch vmcnt
            asm volatile("s_waitcnt lgkmcnt(0)" ::: "memory");
            __builtin_amdgcn_s_barrier();
        }
    }

    // ---- G reduction -> dyn_cent ----
    if (c >= 8) {
        float s = ga0 + ga1 + ga2 + ga3;
        s += __shfl_xor(s, 16, 64);
        s += __shfl_xor(s, 32, 64);
        if (lane < 16) Gred[wq * 8 + (c - 8)] = s;
    }
    __syncthreads();
    if (t < 8) {
        float s = 0.f;
        #pragma unroll
        for (int w = 0; w < 8; ++w) s += Gred[w * 8 + t];
        dc[t] = log1pf(s);
    }
    __syncthreads();

    // ---- e_out phase: all 512 rows from persistent ET ----
    {
        float4 oe[8];
        #pragma unroll
        for (int h = 0; h < 8; ++h)
            oe[h] = ((const float4*)O_e)[h * 32 + c4o];
        float4* __restrict__ out4 = (float4*)e_out + (size_t)bn * NN * 32;
        #pragma unroll 4
        for (int it = 0; it < 32; ++it) {
            const int m = mr0 + it * 16;
            float4 rr{0.f, 0.f, 0.f, 0.f};
            #pragma unroll
            for (int h = 0; h < 8; ++h) {
                const float ev = ET[h * ETS + m];   // broadcast read
                rr.x += ev * oe[h].x;
                rr.y += ev * oe[h].y;
                rr.z += ev * oe[h].z;
                rr.w += ev * oe[h].w;
            }
            out4[m * 32 + c4o] = rr;
        }
    }

    // ---- softmax + AV: wave wq owns head wq ----
    {
        const int h = wq;
        float vals[8];
        float rmax = -1e30f;
        #pragma unroll
        for (int k = 0; k < 8; ++k) {
            vals[k] = ET[h * ETS + k * 64 + lane];
            rmax = fmaxf(rmax, vals[k]);
        }
        #pragma unroll
        for (int off = 32; off >= 1; off >>= 1)
            rmax = fmaxf(rmax, __shfl_xor(rmax, off, 64));
        float sum = 0.f;
        #pragma unroll
        for (int k = 0; k < 8; ++k) sum += __expf(vals[k] - rmax);
        #pragma unroll
        for (int off = 32; off >= 1; off >>= 1)
            sum += __shfl_xor(sum, off, 64);
        const float factor = dc[h] / sum;

        const int ddx = lane & 15, mg = lane >> 4;
        const float* __restrict__ vb = Vw + ((size_t)(b * HH + h) * NN) * DKK;
        float av = 0.f;
        #pragma unroll 4
        for (int m = mg; m < NN; m += 4) {
            const float p = __expf(ET[h * ETS + m] - rmax);
            av += p * vb[m * DKK + ddx];
        }
        av += __shfl_xor(av, 16, 64);
        av += __shfl_xor(av, 32, 64);
        if (mg == 0) vout[h * DKK + ddx] = av * factor;
    }
    __syncthreads();

    // ---- n_out = vout @ O_n ----
    if (t < DD) {
        float a3 = 0.f;
        #pragma unroll 4
        for (int d = 0; d < DD; ++d) a3 += vout[d] * O_n[d * DD + t];
        n_out[(size_t)bn * DD + t] = a3;
    }
    #undef STAGE_LOAD
    #undef STAGE_WRITE
    #undef STAGE_WRITE_ALL
}

extern "C" void kernel_launch(void* const* d_in, const int* in_sizes, int n_in,
                              void* d_out, int out_size, void* d_ws, size_t ws_size,
                              hipStream_t stream)
{
    const float* n_ptr = (const float*)d_in[0];
    const float* e     = (const float*)d_in[1];
    const float* W_qkv = (const float*)d_in[2];
    const float* O_n   = (const float*)d_in[3];
    const float* W_g   = (const float*)d_in[4];
    const float* W_e   = (const float*)d_in[5];
    const float* O_e   = (const float*)d_in[6];

    float* n_out = (float*)d_out;
    float* e_out = n_out + (size_t)BB * NN * DD;

    float* Qw   = (float*)d_ws;                          // 3 x 0.5MB
    float* Kw   = Qw + (size_t)BB * HH * NN * DKK;
    float* Vw   = Kw + (size_t)BB * HH * NN * DKK;
    float* WegT = Vw + (size_t)BB * HH * NN * DKK;       // 8KB

    qkv_kernel<<<BB * NN + 16, 128, 0, stream>>>(n_ptr, W_qkv, W_g, W_e,
                                                 Qw, Kw, Vw, WegT);
    eg_kernel<<<BB * NN, 512, 0, stream>>>(e, WegT, O_e, Qw, Kw, Vw, O_n,
                                           n_out, e_out);
}

// Round 13
// 164.083 us; speedup vs baseline: 2.2604x; 2.2604x over previous
//
#include <hip/hip_runtime.h>
#include <math.h>

#define BB 2
#define NN 512
#define DD 128
#define HH 8
#define DKK 16
#define TR 64            // tile rows
#define NT (NN / TR)     // 8 tiles per (b,n)
#define ETS 516          // padded ET row stride (516 % 32 = 4 -> conflict-free RMW)

typedef __attribute__((ext_vector_type(8))) short short8;
typedef __attribute__((ext_vector_type(4))) float f32x4;

__device__ __forceinline__ float dot4(float4 a, float4 b) {
    return a.x*b.x + a.y*b.y + a.z*b.z + a.w*b.w;
}
// RNE f32 -> bf16 pack (a in low, b in high)
__device__ __forceinline__ unsigned pk_bf16(float a, float b) {
    unsigned ua = __float_as_uint(a), ub = __float_as_uint(b);
    ua = (ua + 0x7FFFu + ((ua >> 16) & 1u)) >> 16;
    ub = (ub + 0x7FFFu + ((ub >> 16) & 1u)) >> 16;
    return ua | (ub << 16);
}

// ---------------- Kernel 1: QKV projection + W_egT staging ----------------
__global__ __launch_bounds__(128)
void qkv_kernel(const float* __restrict__ n_in,
                const float* __restrict__ W_qkv,
                const float* __restrict__ W_g,
                const float* __restrict__ W_e,
                float* __restrict__ Qw, float* __restrict__ Kw,
                float* __restrict__ Vw, float* __restrict__ WegT)
{
    const int bid = blockIdx.x;
    if (bid >= BB * NN) {                    // 16 trailing blocks: WegT[col][d]
        const int col = bid - BB * NN;       // 0..15
        const int t = threadIdx.x;           // 0..127
        WegT[col * DD + t] = (col < 8) ? W_e[t * HH + col]
                                       : W_g[t * HH + (col - 8)];
        return;
    }
    __shared__ float nrow[DD];
    const int bn = bid;
    const int b  = bn >> 9;
    const int nr = bn & 511;
    const int t  = threadIdx.x;
    nrow[t] = n_in[(size_t)bn * DD + t];
    __syncthreads();
    const int h = t >> 4, dk = t & 15;
    const size_t dst = ((size_t)(b * HH + h) * NN + nr) * DKK + dk;
    float accq = 0.f, acck = 0.f, accv = 0.f;
    #pragma unroll 8
    for (int d = 0; d < DD; ++d) {
        const float nv = nrow[d];
        const float* wr = W_qkv + (size_t)d * 3 * DD;
        accq += nv * wr[t];
        acck += nv * wr[t + 128];
        accv += nv * wr[t + 256];
    }
    Qw[dst] = accq;
    Kw[dst] = acck;
    Vw[dst] = accv;
}

// ---------------- Kernel 2: fully fused QK + E/G (MFMA) + e_out + softmax/AV + n_out
// One block per (b,n), 512 threads = 8 waves. TR=64 tiles; MFMA wave-group
// alternates by tile parity. LDS ~33.7KB -> up to 4 blocks/CU; waves_per_eu
// min=4 caps VGPR at 128 (live ~70) so NO spills (R12 lesson: min=8 => 32
// VGPR => 540MB of scratch traffic).
__global__ __attribute__((amdgpu_flat_work_group_size(512, 512),
                          amdgpu_waves_per_eu(4, 8)))
void eg_kernel(const float* __restrict__ e,
               const float* __restrict__ WegT,
               const float* __restrict__ O_e,
               const float* __restrict__ Qw,
               const float* __restrict__ Kw,
               const float* __restrict__ Vw,
               const float* __restrict__ O_n,
               float* __restrict__ n_out,
               float* __restrict__ e_out)
{
    __shared__ __align__(16) uint4 ebuf4[TR * 16];   // 16KB bf16 tile (single)
    __shared__ __align__(16) float ET[HH * ETS];     // 16.5KB persistent _E [h][m]
    __shared__ float Gred[64];
    __shared__ float dc[HH];
    __shared__ __align__(16) float vout[DD];

    const int t    = threadIdx.x;
    const int bn   = blockIdx.x;
    const int b    = bn >> 9;
    const int nr   = bn & 511;
    const int wq   = t >> 6;
    const int lane = t & 63;
    const int c    = lane & 15;      // MFMA C/D col (= W col / head)
    const int mq   = lane >> 4;      // C/D row group; also A/B k-group
    const int wgrp = wq & 3;         // m-block within tile
    const int wpar = wq >> 2;        // group parity (0: even tiles, 1: odd)
    const int c4o  = t & 31;         // e_out float4 column
    const int mr0  = t >> 5;         // e_out row base 0..15

    const float4* __restrict__ e4    = (const float4*)e + (size_t)bn * NN * 32;
    const float4* __restrict__ WegT4 = (const float4*)WegT;

    // ---- B fragments: W[col=c][k] -> bf16, 4 k-steps (16 VGPR) ----
    short8 wB[4];
    #pragma unroll
    for (int kb = 0; kb < 4; ++kb) {
        const float4 wa = WegT4[c * 32 + kb * 8 + mq * 2];
        const float4 wb = WegT4[c * 32 + kb * 8 + mq * 2 + 1];
        uint4 u;
        u.x = pk_bf16(wa.x, wa.y); u.y = pk_bf16(wa.z, wa.w);
        u.z = pk_bf16(wb.x, wb.y); u.w = pk_bf16(wb.z, wb.w);
        wB[kb] = *(short8*)&u;
    }

    // stage-load regs: 4 float4 (16 VGPR)
    float4 pa0, pb0, pa1, pb1;

    #define STAGE_LOAD(tile)                                                  \
    {                                                                         \
        const float4* __restrict__ sp = e4 + (size_t)(tile) * 2048 + 2 * t;   \
        pa0 = sp[0];    pb0 = sp[1];                                          \
        pa1 = sp[1024]; pb1 = sp[1025];                                       \
    }
    // uint4 u covers f32-float4 pair (2u, 2u+1); row = u>>4, col ck = u&15
    #define STAGE_WRITE(U, A, B)                                              \
    {                                                                         \
        const int u_ = (U), ms = u_ >> 4, ck = u_ & 15;                       \
        uint4 x;                                                              \
        x.x = pk_bf16(A.x, A.y); x.y = pk_bf16(A.z, A.w);                     \
        x.z = pk_bf16(B.x, B.y); x.w = pk_bf16(B.z, B.w);                     \
        ebuf4[ms * 16 + (ck ^ (ms & 15))] = x;                                \
    }
    #define STAGE_WRITE_ALL()                                                 \
    {                                                                         \
        STAGE_WRITE(t, pa0, pb0); STAGE_WRITE(t + 512, pa1, pb1);             \
    }

    float ga0 = 0.f, ga1 = 0.f, ga2 = 0.f, ga3 = 0.f;

    // ---- prologue: issue tile-0 e loads (HBM), then QK scores (L2) ----
    STAGE_LOAD(0);

    {   // wave wq = head h; clamped scores -> ET[h][m]
        const int h = wq;
        const float4* __restrict__ qp =
            (const float4*)(Qw + ((size_t)(b * HH + h) * NN + nr) * DKK);
        const float4 q0 = qp[0], q1 = qp[1], q2 = qp[2], q3 = qp[3];
        const float4* __restrict__ kb =
            (const float4*)(Kw + ((size_t)(b * HH + h) * NN) * DKK);
        #pragma unroll
        for (int k = 0; k < 8; ++k) {
            const int m = k * 64 + lane;
            float s = dot4(q0, kb[m * 4 + 0]) + dot4(q1, kb[m * 4 + 1])
                    + dot4(q2, kb[m * 4 + 2]) + dot4(q3, kb[m * 4 + 3]);
            s *= 0.25f;
            ET[h * ETS + m] = fminf(5.f, fmaxf(-5.f, s));
        }
    }

    STAGE_WRITE_ALL();
    asm volatile("s_waitcnt lgkmcnt(0)" ::: "memory");
    __builtin_amdgcn_s_barrier();

    #pragma unroll
    for (int tt = 0; tt < NT; ++tt) {
        // prefetch next tile into regs (stays in flight across the MFMA)
        if (tt + 1 < NT) STAGE_LOAD(tt + 1);

        // ---- MFMA: tile parity selects the active 4-wave group ----
        if (wpar == (tt & 1)) {
            const int mrow = wgrp * 16 + c;
            f32x4 acc = {0.f, 0.f, 0.f, 0.f};
            #pragma unroll
            for (int kb = 0; kb < 4; ++kb) {
                const int ck = kb * 4 + mq;
                uint4 av = ebuf4[mrow * 16 + (ck ^ (mrow & 15))];
                acc = __builtin_amdgcn_mfma_f32_16x16x32_bf16(
                          *(short8*)&av, wB[kb], acc, 0, 0, 0);
            }
            // ---- epilogue: _E = acc + clamped_score (LDS RMW) / G accumulate ----
            const int mloc = tt * TR + wgrp * 16 + mq * 4;
            if (c < 8) {
                float4 prev = *(float4*)&ET[c * ETS + mloc];
                prev.x += acc[0]; prev.y += acc[1];
                prev.z += acc[2]; prev.w += acc[3];
                *(float4*)&ET[c * ETS + mloc] = prev;
            } else {
                ga0 += 1.f / (1.f + __expf(-acc[0]));
                ga1 += 1.f / (1.f + __expf(-acc[1]));
                ga2 += 1.f / (1.f + __expf(-acc[2]));
                ga3 += 1.f / (1.f + __expf(-acc[3]));
            }
        }
        asm volatile("s_waitcnt lgkmcnt(0)" ::: "memory");
        __builtin_amdgcn_s_barrier();   // ebuf reads done; ET writes visible

        // ---- refill ebuf from prefetched regs ----
        if (tt + 1 < NT) {
            STAGE_WRITE_ALL();          // compiler waits the prefetch vmcnt
            asm volatile("s_waitcnt lgkmcnt(0)" ::: "memory");
            __builtin_amdgcn_s_barrier();
        }
    }

    // ---- G reduction -> dyn_cent ----
    if (c >= 8) {
        float s = ga0 + ga1 + ga2 + ga3;
        s += __shfl_xor(s, 16, 64);
        s += __shfl_xor(s, 32, 64);
        if (lane < 16) Gred[wq * 8 + (c - 8)] = s;
    }
    __syncthreads();
    if (t < 8) {
        float s = 0.f;
        #pragma unroll
        for (int w = 0; w < 8; ++w) s += Gred[w * 8 + t];
        dc[t] = log1pf(s);
    }
    __syncthreads();

    // ---- e_out phase: all 512 rows from persistent ET ----
    {
        float4 oe[8];
        #pragma unroll
        for (int h = 0; h < 8; ++h)
            oe[h] = ((const float4*)O_e)[h * 32 + c4o];
        float4* __restrict__ out4 = (float4*)e_out + (size_t)bn * NN * 32;
        #pragma unroll 4
        for (int it = 0; it < 32; ++it) {
            const int m = mr0 + it * 16;
            float4 rr{0.f, 0.f, 0.f, 0.f};
            #pragma unroll
            for (int h = 0; h < 8; ++h) {
                const float ev = ET[h * ETS + m];   // broadcast read
                rr.x += ev * oe[h].x;
                rr.y += ev * oe[h].y;
                rr.z += ev * oe[h].z;
                rr.w += ev * oe[h].w;
            }
            out4[m * 32 + c4o] = rr;
        }
    }

    // ---- softmax + AV: wave wq owns head wq ----
    {
        const int h = wq;
        float vals[8];
        float rmax = -1e30f;
        #pragma unroll
        for (int k = 0; k < 8; ++k) {
            vals[k] = ET[h * ETS + k * 64 + lane];
            rmax = fmaxf(rmax, vals[k]);
        }
        #pragma unroll
        for (int off = 32; off >= 1; off >>= 1)
            rmax = fmaxf(rmax, __shfl_xor(rmax, off, 64));
        float sum = 0.f;
        #pragma unroll
        for (int k = 0; k < 8; ++k) sum += __expf(vals[k] - rmax);
        #pragma unroll
        for (int off = 32; off >= 1; off >>= 1)
            sum += __shfl_xor(sum, off, 64);
        const float factor = dc[h] / sum;

        const int ddx = lane & 15, mg = lane >> 4;
        const float* __restrict__ vb = Vw + ((size_t)(b * HH + h) * NN) * DKK;
        float av = 0.f;
        #pragma unroll 4
        for (int m = mg; m < NN; m += 4) {
            const float p = __expf(ET[h * ETS + m] - rmax);
            av += p * vb[m * DKK + ddx];
        }
        av += __shfl_xor(av, 16, 64);
        av += __shfl_xor(av, 32, 64);
        if (mg == 0) vout[h * DKK + ddx] = av * factor;
    }
    __syncthreads();

    // ---- n_out = vout @ O_n ----
    if (t < DD) {
        float a3 = 0.f;
        #pragma unroll 4
        for (int d = 0; d < DD; ++d) a3 += vout[d] * O_n[d * DD + t];
        n_out[(size_t)bn * DD + t] = a3;
    }
    #undef STAGE_LOAD
    #undef STAGE_WRITE
    #undef STAGE_WRITE_ALL
}

extern "C" void kernel_launch(void* const* d_in, const int* in_sizes, int n_in,
                              void* d_out, int out_size, void* d_ws, size_t ws_size,
                              hipStream_t stream)
{
    const float* n_ptr = (const float*)d_in[0];
    const float* e     = (const float*)d_in[1];
    const float* W_qkv = (const float*)d_in[2];
    const float* O_n   = (const float*)d_in[3];
    const float* W_g   = (const float*)d_in[4];
    const float* W_e   = (const float*)d_in[5];
    const float* O_e   = (const float*)d_in[6];

    float* n_out = (float*)d_out;
    float* e_out = n_out + (size_t)BB * NN * DD;

    float* Qw   = (float*)d_ws;                          // 3 x 0.5MB
    float* Kw   = Qw + (size_t)BB * HH * NN * DKK;
    float* Vw   = Kw + (size_t)BB * HH * NN * DKK;
    float* WegT = Vw + (size_t)BB * HH * NN * DKK;       // 8KB

    qkv_kernel<<<BB * NN + 16, 128, 0, stream>>>(n_ptr, W_qkv, W_g, W_e,
                                                 Qw, Kw, Vw, WegT);
    eg_kernel<<<BB * NN, 512, 0, stream>>>(e, WegT, O_e, Qw, Kw, Vw, O_n,
                                           n_out, e_out);
}